// Round 14
// baseline (267.011 us; speedup 1.0000x reference)
//
#include <hip/hip_runtime.h>

#define Bn 8
#define Nn 4096
#define Pn 4096
#define Kn 32
#define Cn 128

using float4v = __attribute__((ext_vector_type(4))) float;
using short8  = __attribute__((ext_vector_type(8))) short;

__device__ __forceinline__ unsigned short bf16b(float f) {
  union { float f; unsigned u; } v; v.f = f;
  unsigned r = v.u + 0x7FFFu + ((v.u >> 16) & 1u);   // round-nearest-even
  return (unsigned short)(r >> 16);
}

// (hi16(x)) | (hi16(y)<<16) — truncating f32->bf16 pair pack, one v_perm_b32
__device__ __forceinline__ unsigned pkhi(float x, float y) {
  return __builtin_amdgcn_perm(__float_as_uint(y), __float_as_uint(x), 0x07060302u);
}

// ---------------------------------------------------------------------------
// prep: blocks 0-63: WlT[n][k] = bf16(Wl[k][n]); blocks 64-95: xyz copy into
// d_out (+ block 64 zeroes gacc).   (R7 shell, best-measured end-to-end)
// ---------------------------------------------------------------------------
__global__ __launch_bounds__(256) void prep(const float* __restrict__ Wl,
                                            unsigned short* __restrict__ WlT,
                                            const float* __restrict__ xyz,
                                            float* __restrict__ out,
                                            float* __restrict__ gacc) {
  __shared__ unsigned short tile[128 * 33];   // [n][kl], +1 pad
  const int t = threadIdx.x, blk = blockIdx.x;
  if (blk < 64) {
#pragma unroll
    for (int i = 0; i < 16; ++i) {
      int idx = i * 256 + t;                  // 0..4095
      int kl = idx >> 7, n = idx & 127;
      tile[n * 33 + kl] = bf16b(Wl[(size_t)(blk * 32 + kl) * 128 + n]);
    }
    __syncthreads();
#pragma unroll
    for (int i = 0; i < 16; ++i) {
      int idx = i * 256 + t;
      int n = idx >> 5, kl = idx & 31;
      WlT[(size_t)n * 2048 + blk * 32 + kl] = tile[n * 33 + kl];
    }
  } else {
    if (blk == 64) gacc[t] = 0.f;
    const int i0 = (blk - 64) * 3072 + t * 12;   // 32 blocks x 3072 f32
#pragma unroll
    for (int i = 0; i < 3; ++i)
      *(float4v*)(out + i0 + i * 4) = *(const float4v*)(xyz + i0 + i * 4);
  }
}

// ---------------------------------------------------------------------------
// fused v11 (ONE wait per ct): 2048 blocks x 4 waves x 16 points. The full
// ct-batch of gathers (4 pts x 8 DMA, zero dest VGPRs) fits LDS at 16 pts/
// block (slab 32K + Mlds 8K + nlds 2K + red 1K = 44K, 3 blocks/CU). All 32
// DMAs for ct+1 issue in one burst at the END of phase A (after every
// b-load consumption — in-order-vmcnt safe), survive the barrier because
// barriers are raw s_barrier (no __syncthreads vmcnt(0) drain), and phase B
// opens with a single vmcnt(0): waits/ct/wave = 1 (was 8 in every 105-us
// variant). Components verified: R8 DMA slab layout, R9 16-pt phase A +
// epilogue numerics, R7 shell.
// ---------------------------------------------------------------------------
__global__ __launch_bounds__(256, 4) void fused(
    const float* __restrict__ points, const float* __restrict__ lc,
    const int* __restrict__ nl, const int* __restrict__ didx,
    const float* __restrict__ Ww, const float* __restrict__ bwv,
    const unsigned short* __restrict__ WlT, const float* __restrict__ blv,
    float* __restrict__ xout, float* __restrict__ gacc) {
  __shared__ float slab[4][4][512];           // 32 KB: wave x point x 2KB
  __shared__ unsigned short Mlds[16 * 256];   // 8 KB, two-sided XOR swizzle
  __shared__ int nlds[16 * 32];               // 2 KB, pre-shifted byte offsets
  __shared__ float red[256];                  // 1 KB   (total 43 KB)

  const int t = threadIdx.x, lane = t & 63, w = t >> 6;
  const int l15 = lane & 15, q = lane >> 4;
  const int b = blockIdx.x & 7;               // XCD-affine batch
  const int pg = blockIdx.x >> 3;             // 0..255
  const int p0 = pg * 16;
  const int db = didx[b];
  const char* __restrict__ pbase = (const char*)(points + (size_t)db * Nn * Cn);

  // stage neighbor ids, pre-shifted to byte row offsets (row stride 512 B)
  {
    int2 nv = *(const int2*)(nl + (size_t)(db * Pn + p0) * Kn + t * 2);
    nv.x <<= 9; nv.y <<= 9;
    *(int2*)&nlds[t * 2] = nv;
  }

  const float Ww0 = Ww[l15], Ww1 = Ww[16 + l15], Ww2 = Ww[32 + l15];
  const float bw0 = bwv[l15];

  float4v acc[2];
  acc[0] = (float4v){0.f, 0.f, 0.f, 0.f};
  acc[1] = (float4v){0.f, 0.f, 0.f, 0.f};

  __syncthreads();   // nlds ready

  // weight A-frags for my 4 points: A[m=w_out=l15][k=q*8+j]
  short8 af[4];
#pragma unroll
  for (int i = 0; i < 4; ++i) {
    const int p = p0 + w * 4 + i;
    const int pk = (db * Pn + p) * Kn;
    const float* __restrict__ lcp = lc + (size_t)(pk + q * 8) * 3;
    float la[24];
#pragma unroll
    for (int v = 0; v < 6; ++v) *(float4v*)&la[v * 4] = *(const float4v*)(lcp + v * 4);
#pragma unroll
    for (int j = 0; j < 8; ++j) {
      float ww = bw0 + la[3 * j] * Ww0 + la[3 * j + 1] * Ww1 + la[3 * j + 2] * Ww2;
      af[i][j] = (short)bf16b(ww);
    }
  }

  // my n-slice: channels w*32 .. w*32+31
  const unsigned short* __restrict__ bpt =
      WlT + (size_t)(w * 32 + l15) * 2048 + q * 8;
  const unsigned cvoff = (unsigned)(l15 * 4);

#define WAITV0 asm volatile("s_waitcnt vmcnt(0)" ::: "memory")
#define LGKM0  asm volatile("s_waitcnt lgkmcnt(0)" ::: "memory")
#define SBAR   __builtin_amdgcn_sched_barrier(0)

// issue 8 LDS-DMA gathers for point (i), chunk (ct) into slab[w][i]
#define DMA(i, ct)                                                         \
  {                                                                        \
    const int pi_ = w * 4 + (i);                                           \
    int nk_[8];                                                            \
    *(int4*)&nk_[0] = *(const int4*)&nlds[pi_ * 32 + q * 8];               \
    *(int4*)&nk_[4] = *(const int4*)&nlds[pi_ * 32 + q * 8 + 4];           \
    _Pragma("unroll") for (int j = 0; j < 8; ++j)                          \
        __builtin_amdgcn_global_load_lds(                                  \
            (const __attribute__((address_space(1))) unsigned int*)        \
                (pbase + ((unsigned)nk_[j] + cvoff + (unsigned)((ct) * 64))), \
            (__attribute__((address_space(3))) unsigned int*)              \
                (&slab[w][i][(j) * 64]),                                   \
            4, 0, 0);                                                      \
  }

// read slab buffer (i) then pack + step1 MFMA + swizzled Mlds write
#define FIN(i)                                                             \
  {                                                                        \
    const int pi_ = w * 4 + (i);                                           \
    float f_[8];                                                           \
    const float* ls_ = &slab[w][i][(unsigned)(q * 16 + l15)];              \
    _Pragma("unroll") for (int j = 0; j < 8; ++j) f_[j] = ls_[j * 64];     \
    union { short8 s; unsigned u[4]; } bv_;                                \
    bv_.u[0] = pkhi(f_[0], f_[1]);                                         \
    bv_.u[1] = pkhi(f_[2], f_[3]);                                         \
    bv_.u[2] = pkhi(f_[4], f_[5]);                                         \
    bv_.u[3] = pkhi(f_[6], f_[7]);                                         \
    float4v d_ = {0.f, 0.f, 0.f, 0.f};                                     \
    d_ = __builtin_amdgcn_mfma_f32_16x16x32_bf16(af[i], bv_.s, d_, 0, 0, 0); \
    const unsigned off_ = (unsigned)(pi_ * 512 + ((l15 * 32 + q * 8) ^     \
        ((((pi_ & 7) ^ (l15 & 7)) & 7) << 4)));                            \
    uint2 u_;                                                              \
    u_.x = pkhi(d_[0], d_[1]);                                             \
    u_.y = pkhi(d_[2], d_[3]);                                             \
    *(uint2*)((char*)Mlds + off_) = u_;                                    \
  }

  // prologue: whole ct=0 batch in flight (32 DMA, zero dest VGPRs)
  SBAR;
  DMA(0, 0) DMA(1, 0) DMA(2, 0) DMA(3, 0)

  for (int ct = 0; ct < 8; ++ct) {
    // ---- phase B: ONE wait, then 4 wait-free FINs
    WAITV0; SBAR;
    FIN(0) FIN(1) FIN(2) FIN(3)
    LGKM0; SBAR;
    __builtin_amdgcn_s_barrier();             // barrier 1: Mlds ready
    // ---- phase A: Y += Mchunk @ WlT-chunk for my 32 channels
    const unsigned short* __restrict__ bp = bpt + ct * 256;
    short8 b0A = *(const short8*)(bp);
    short8 b1A = *(const short8*)(bp + 32768);
    __builtin_amdgcn_s_setprio(1);
#pragma unroll
    for (int ks = 0; ks < 8; ++ks) {
      short8 b0B, b1B;
      if (ks < 7) {
        b0B = *(const short8*)(bp + (ks + 1) * 32);
        b1B = *(const short8*)(bp + 32768 + (ks + 1) * 32);
      }
      const unsigned ax = (unsigned)((ks * 64 + q * 16) ^
          ((((l15 & 7) ^ ((ks * 2 + (q >> 1)) & 7)) & 7) << 4));
      short8 a0 = *(const short8*)((const char*)Mlds + l15 * 512 + ax);
      acc[0] = __builtin_amdgcn_mfma_f32_16x16x32_bf16(a0, b0A, acc[0], 0, 0, 0);
      acc[1] = __builtin_amdgcn_mfma_f32_16x16x32_bf16(a0, b1A, acc[1], 0, 0, 0);
      b0A = b0B; b1A = b1B;
    }
    __builtin_amdgcn_s_setprio(0);
    // issue next ct's WHOLE batch after all b-loads consumed (in-order
    // vmcnt safe); raw s_barrier below has no vmcnt drain -> stays in flight
    if (ct < 7) {
      SBAR;
      DMA(0, ct + 1) DMA(1, ct + 1) DMA(2, ct + 1) DMA(3, ct + 1)
    }
    SBAR;
    __builtin_amdgcn_s_barrier();             // barrier 2: Mlds reusable
  }
#undef DMA
#undef FIN
#undef WAITV0
#undef LGKM0
#undef SBAR

  // epilogue: bias, transposed store (B,C,P), disjoint per-wave channel stats
#pragma unroll
  for (int nt = 0; nt < 2; ++nt) {
    const int ch = w * 32 + nt * 16 + l15;
    const float bb = blv[ch];
    float s = 0.f, sq = 0.f;
    float4v o;
#pragma unroll
    for (int r = 0; r < 4; ++r) {
      float v = acc[nt][r] + bb; o[r] = v; s += v; sq += v * v;
    }
    *(float4v*)(xout + ((size_t)(b * Cn + ch)) * Pn + p0 + q * 4) = o;
    s += __shfl_xor(s, 16); s += __shfl_xor(s, 32);
    sq += __shfl_xor(sq, 16); sq += __shfl_xor(sq, 32);
    if (lane < 16) { red[ch] = s; red[128 + ch] = sq; }
  }
  __syncthreads();
  atomicAdd(&gacc[t], red[t]);
}

// ---------------------------------------------------------------------------
// finalize: layernorm (per-channel over B*P) + relu, in place on x chunk
// ---------------------------------------------------------------------------
__global__ __launch_bounds__(256) void finalize_ln(float* __restrict__ x,
                                                   const float* __restrict__ gacc,
                                                   const float* __restrict__ gamma,
                                                   const float* __restrict__ beta) {
  const int idx = blockIdx.x * 256 + threadIdx.x;
  const int fi = idx * 4;
  const int c = (fi >> 12) & 127;
  const float inv = 1.f / 32768.f;
  const float mean = gacc[c] * inv;
  const float var = gacc[128 + c] * inv - mean * mean;
  const float scale = rsqrtf(var + 1e-5f) * gamma[c];
  const float shift = beta[c] - mean * scale;
  float4v v = *(float4v*)(x + fi);
#pragma unroll
  for (int r = 0; r < 4; ++r) v[r] = fmaxf(v[r] * scale + shift, 0.f);
  *(float4v*)(x + fi) = v;
}

extern "C" void kernel_launch(void* const* d_in, const int* in_sizes, int n_in,
                              void* d_out, int out_size, void* d_ws, size_t ws_size,
                              hipStream_t stream) {
  const float* xyz    = (const float*)d_in[0];
  const float* points = (const float*)d_in[1];
  const float* lc     = (const float*)d_in[2];
  const int*   nl     = (const int*)d_in[3];
  const int*   didx   = (const int*)d_in[4];
  const float* Ww     = (const float*)d_in[5];
  const float* bw     = (const float*)d_in[6];
  const float* Wl     = (const float*)d_in[7];
  const float* bl     = (const float*)d_in[8];
  const float* gamma  = (const float*)d_in[9];
  const float* beta   = (const float*)d_in[10];

  float* out  = (float*)d_out;
  float* xout = out + (size_t)Bn * Pn * 3;                       // x chunk (B,C,P)
  unsigned short* WlT = (unsigned short*)d_ws;                   // 512 KB
  float* gacc = (float*)((char*)d_ws + (size_t)512 * 1024);      // 1 KB

  prep<<<96, 256, 0, stream>>>(Wl, WlT, xyz, out, gacc);
  fused<<<2048, 256, 0, stream>>>(points, lc, nl, didx, Ww, bw, WlT, bl,
                                  xout, gacc);
  finalize_ln<<<4096, 256, 0, stream>>>(xout, gacc, gamma, beta);
}

// Round 15
// 193.564 us; speedup vs baseline: 1.3794x; 1.3794x over previous
//
#include <hip/hip_runtime.h>

#define Bn 8
#define Nn 4096
#define Pn 4096
#define Kn 32
#define Cn 128

using float4v = __attribute__((ext_vector_type(4))) float;
using short8  = __attribute__((ext_vector_type(8))) short;

__device__ __forceinline__ unsigned short bf16b(float f) {
  union { float f; unsigned u; } v; v.f = f;
  unsigned r = v.u + 0x7FFFu + ((v.u >> 16) & 1u);   // round-nearest-even
  return (unsigned short)(r >> 16);
}

// (hi16(x)) | (hi16(y)<<16) — truncating f32->bf16 pair pack, one v_perm_b32
__device__ __forceinline__ unsigned pkhi(float x, float y) {
  return __builtin_amdgcn_perm(__float_as_uint(y), __float_as_uint(x), 0x07060302u);
}

// ---------------------------------------------------------------------------
// prep: blocks 0-63: WlT[n][k] = bf16(Wl[k][n]); blocks 64-95: xyz copy into
// d_out (+ block 64 zeroes gacc).   (R7 shell — best measured end-to-end)
// ---------------------------------------------------------------------------
__global__ __launch_bounds__(256) void prep(const float* __restrict__ Wl,
                                            unsigned short* __restrict__ WlT,
                                            const float* __restrict__ xyz,
                                            float* __restrict__ out,
                                            float* __restrict__ gacc) {
  __shared__ unsigned short tile[128 * 33];   // [n][kl], +1 pad
  const int t = threadIdx.x, blk = blockIdx.x;
  if (blk < 64) {
#pragma unroll
    for (int i = 0; i < 16; ++i) {
      int idx = i * 256 + t;                  // 0..4095
      int kl = idx >> 7, n = idx & 127;
      tile[n * 33 + kl] = bf16b(Wl[(size_t)(blk * 32 + kl) * 128 + n]);
    }
    __syncthreads();
#pragma unroll
    for (int i = 0; i < 16; ++i) {
      int idx = i * 256 + t;
      int n = idx >> 5, kl = idx & 31;
      WlT[(size_t)n * 2048 + blk * 32 + kl] = tile[n * 33 + kl];
    }
  } else {
    if (blk == 64) gacc[t] = 0.f;
    const int i0 = (blk - 64) * 3072 + t * 12;   // 32 blocks x 3072 f32
#pragma unroll
    for (int i = 0; i < 3; ++i)
      *(float4v*)(out + i0 + i * 4) = *(const float4v*)(xyz + i0 + i * 4);
  }
}

// ---------------------------------------------------------------------------
// fused v12 — PRODUCER/CONSUMER WAVE SPECIALIZATION (the untried structural
// lever; AITER pattern). 1024 blocks x 8 waves x 32 points:
//   waves 0-3 (producers): R7 phase-B verbatim — register-ring gathers +
//     step1 MFMA + two-sided-XOR Mlds writes, 8 points each, into
//     double-buffered Mlds[ct&1].
//   waves 4-7 (consumers): R7 phase-A verbatim — step2 MFMA over the OTHER
//     Mlds buffer (ct-1), 32 channels each, acc in registers.
// One __syncthreads per ct; consumers lag producers by 1 ct. Producer gather
// stalls are covered by consumer MFMA on the same SIMD (2P+2C waves/SIMD)
// WITHIN the block — critical path per ct = max(B,A) instead of B+A.
// Numerics: identical op order to R7 for both stages -> absmax unchanged.
// LDS 37 KB (Mlds 2x16K + nlds 4K + red 1K).
// ---------------------------------------------------------------------------
__global__ __launch_bounds__(512, 4) void fused(
    const float* __restrict__ points, const float* __restrict__ lc,
    const int* __restrict__ nl, const int* __restrict__ didx,
    const float* __restrict__ Ww, const float* __restrict__ bwv,
    const unsigned short* __restrict__ WlT, const float* __restrict__ blv,
    float* __restrict__ xout, float* __restrict__ gacc) {
  __shared__ unsigned short Mlds[2][32 * 256];   // 32 KB, double-buffered
  __shared__ int nlds[32 * 32];                  // 4 KB, pre-shifted offsets
  __shared__ float red[256];                     // 1 KB

  const int t = threadIdx.x, lane = t & 63, w = t >> 6;   // w = 0..7
  const int l15 = lane & 15, q = lane >> 4;
  const int b = blockIdx.x & 7;               // XCD-affine batch
  const int pg = blockIdx.x >> 3;             // 0..127
  const int p0 = pg * 32;
  const int db = didx[b];
  const char* __restrict__ pbase = (const char*)(points + (size_t)db * Nn * Cn);
  const bool prod = (w < 4);

  // stage neighbor ids (512 threads, int2 each), pre-shifted <<9
  {
    int2 nv = *(const int2*)(nl + (size_t)(db * Pn + p0) * Kn + t * 2);
    nv.x <<= 9; nv.y <<= 9;
    *(int2*)&nlds[t * 2] = nv;
  }

  // producer-only: weight A-frags for my 8 points (R7 verbatim, w in 0..3)
  short8 af[8];
  if (prod) {
    const float Ww0 = Ww[l15], Ww1 = Ww[16 + l15], Ww2 = Ww[32 + l15];
    const float bw0 = bwv[l15];
#pragma unroll
    for (int i = 0; i < 8; ++i) {
      const int p = p0 + w * 8 + i;
      const int pk = (db * Pn + p) * Kn;
      const float* __restrict__ lcp = lc + (size_t)(pk + q * 8) * 3;
      float la[24];
#pragma unroll
      for (int v = 0; v < 6; ++v) *(float4v*)&la[v * 4] = *(const float4v*)(lcp + v * 4);
#pragma unroll
      for (int j = 0; j < 8; ++j) {
        float ww = bw0 + la[3 * j] * Ww0 + la[3 * j + 1] * Ww1 + la[3 * j + 2] * Ww2;
        af[i][j] = (short)bf16b(ww);
      }
    }
  }

  float4v acc[2][2];
#pragma unroll
  for (int pt = 0; pt < 2; ++pt)
#pragma unroll
    for (int nt = 0; nt < 2; ++nt) acc[pt][nt] = (float4v){0.f, 0.f, 0.f, 0.f};

  __syncthreads();   // nlds ready

  // consumer n-slice: channels (w&3)*32 .. +31
  const unsigned short* __restrict__ bpt =
      WlT + (size_t)((w & 3) * 32 + l15) * 2048 + q * 8;
  const unsigned cvoff = (unsigned)(l15 * 4);

// issue 8 gathers for point (i), chunk (ct) into fdst[8]
#define ISSUE(i, ct, fdst)                                                 \
  {                                                                        \
    const int pi_ = w * 8 + (i);                                           \
    int nk_[8];                                                            \
    *(int4*)&nk_[0] = *(const int4*)&nlds[pi_ * 32 + q * 8];               \
    *(int4*)&nk_[4] = *(const int4*)&nlds[pi_ * 32 + q * 8 + 4];           \
    _Pragma("unroll") for (int j = 0; j < 8; ++j)                          \
        fdst[j] = *(const float*)(pbase + ((unsigned)nk_[j] + cvoff +      \
                                           (unsigned)((ct) * 64)));        \
  }

// pack + step1 MFMA + two-sided-swizzled ds_write into buffer (bsel)
#define FIN(i, bsel, fsrc)                                                 \
  {                                                                        \
    const int pi_ = w * 8 + (i);                                           \
    union { short8 s; unsigned u[4]; } bv_;                                \
    bv_.u[0] = pkhi(fsrc[0], fsrc[1]);                                     \
    bv_.u[1] = pkhi(fsrc[2], fsrc[3]);                                     \
    bv_.u[2] = pkhi(fsrc[4], fsrc[5]);                                     \
    bv_.u[3] = pkhi(fsrc[6], fsrc[7]);                                     \
    float4v d_ = {0.f, 0.f, 0.f, 0.f};                                     \
    d_ = __builtin_amdgcn_mfma_f32_16x16x32_bf16(af[i], bv_.s, d_, 0, 0, 0); \
    const unsigned off_ = (unsigned)((bsel) * 16384 + pi_ * 512 +          \
        ((l15 * 32 + q * 8) ^ ((((pi_ & 7) ^ (l15 & 7)) & 7) << 4)));      \
    uint2 u_;                                                              \
    u_.x = pkhi(d_[0], d_[1]);                                             \
    u_.y = pkhi(d_[2], d_[3]);                                             \
    *(uint2*)((char*)Mlds + off_) = u_;                                    \
  }

  float fb[4][8];   // producer 4-point lookahead ring (static indices)

#pragma unroll 1
  for (int it = 0; it < 9; ++it) {
    if (prod) {
      if (it < 8) {
        const int ct = it, bsel = it & 1;
        ISSUE(0, ct, fb[0])
        ISSUE(1, ct, fb[1])
        ISSUE(2, ct, fb[2])
        ISSUE(3, ct, fb[3])
#pragma unroll
        for (int i = 0; i < 8; ++i) {
          FIN(i, bsel, fb[i & 3])
          if (i + 4 < 8) ISSUE(i + 4, ct, fb[i & 3])
        }
      }
    } else {
      if (it > 0) {
        const int ct = it - 1;
        const char* mb = (const char*)Mlds + (ct & 1) * 16384;
        const unsigned short* __restrict__ bp = bpt + ct * 256;
        short8 b0A = *(const short8*)(bp);
        short8 b1A = *(const short8*)(bp + 32768);
        __builtin_amdgcn_s_setprio(1);
#pragma unroll
        for (int ks = 0; ks < 8; ++ks) {
          short8 b0B, b1B;
          if (ks < 7) {
            b0B = *(const short8*)(bp + (ks + 1) * 32);
            b1B = *(const short8*)(bp + 32768 + (ks + 1) * 32);
          }
          const unsigned ax = (unsigned)((ks * 64 + q * 16) ^
              ((((l15 & 7) ^ ((ks * 2 + (q >> 1)) & 7)) & 7) << 4));
          short8 a0 = *(const short8*)(mb + l15 * 512 + ax);
          short8 a1 = *(const short8*)(mb + (16 + l15) * 512 + ax);
          acc[0][0] = __builtin_amdgcn_mfma_f32_16x16x32_bf16(a0, b0A, acc[0][0], 0, 0, 0);
          acc[0][1] = __builtin_amdgcn_mfma_f32_16x16x32_bf16(a0, b1A, acc[0][1], 0, 0, 0);
          acc[1][0] = __builtin_amdgcn_mfma_f32_16x16x32_bf16(a1, b0A, acc[1][0], 0, 0, 0);
          acc[1][1] = __builtin_amdgcn_mfma_f32_16x16x32_bf16(a1, b1A, acc[1][1], 0, 0, 0);
          b0A = b0B; b1A = b1B;
        }
        __builtin_amdgcn_s_setprio(0);
      }
    }
    __syncthreads();   // producers done writing buf[it&1]; consumers done
                       // reading buf[(it-1)&1]; safe to proceed
  }
#undef ISSUE
#undef FIN

  // epilogue (consumers): bias, transposed store, per-wave channel stats
  if (!prod) {
#pragma unroll
    for (int nt = 0; nt < 2; ++nt) {
      const int ch = (w & 3) * 32 + nt * 16 + l15;
      const float bb = blv[ch];
      float s = 0.f, sq = 0.f;
#pragma unroll
      for (int pt = 0; pt < 2; ++pt) {
        float4v o;
#pragma unroll
        for (int r = 0; r < 4; ++r) {
          float v = acc[pt][nt][r] + bb; o[r] = v; s += v; sq += v * v;
        }
        *(float4v*)(xout + ((size_t)(b * Cn + ch)) * Pn + p0 + pt * 16 + q * 4) = o;
      }
      s += __shfl_xor(s, 16); s += __shfl_xor(s, 32);
      sq += __shfl_xor(sq, 16); sq += __shfl_xor(sq, 32);
      if (lane < 16) { red[ch] = s; red[128 + ch] = sq; }
    }
  }
  __syncthreads();
  if (t < 256) atomicAdd(&gacc[t], red[t]);
}

// ---------------------------------------------------------------------------
// finalize: layernorm (per-channel over B*P) + relu, in place on x chunk
// ---------------------------------------------------------------------------
__global__ __launch_bounds__(256) void finalize_ln(float* __restrict__ x,
                                                   const float* __restrict__ gacc,
                                                   const float* __restrict__ gamma,
                                                   const float* __restrict__ beta) {
  const int idx = blockIdx.x * 256 + threadIdx.x;
  const int fi = idx * 4;
  const int c = (fi >> 12) & 127;
  const float inv = 1.f / 32768.f;
  const float mean = gacc[c] * inv;
  const float var = gacc[128 + c] * inv - mean * mean;
  const float scale = rsqrtf(var + 1e-5f) * gamma[c];
  const float shift = beta[c] - mean * scale;
  float4v v = *(float4v*)(x + fi);
#pragma unroll
  for (int r = 0; r < 4; ++r) v[r] = fmaxf(v[r] * scale + shift, 0.f);
  *(float4v*)(x + fi) = v;
}

extern "C" void kernel_launch(void* const* d_in, const int* in_sizes, int n_in,
                              void* d_out, int out_size, void* d_ws, size_t ws_size,
                              hipStream_t stream) {
  const float* xyz    = (const float*)d_in[0];
  const float* points = (const float*)d_in[1];
  const float* lc     = (const float*)d_in[2];
  const int*   nl     = (const int*)d_in[3];
  const int*   didx   = (const int*)d_in[4];
  const float* Ww     = (const float*)d_in[5];
  const float* bw     = (const float*)d_in[6];
  const float* Wl     = (const float*)d_in[7];
  const float* bl     = (const float*)d_in[8];
  const float* gamma  = (const float*)d_in[9];
  const float* beta   = (const float*)d_in[10];

  float* out  = (float*)d_out;
  float* xout = out + (size_t)Bn * Pn * 3;                       // x chunk (B,C,P)
  unsigned short* WlT = (unsigned short*)d_ws;                   // 512 KB
  float* gacc = (float*)((char*)d_ws + (size_t)512 * 1024);      // 1 KB

  prep<<<96, 256, 0, stream>>>(Wl, WlT, xyz, out, gacc);
  fused<<<1024, 512, 0, stream>>>(points, lc, nl, didx, Ww, bw, WlT, bl,
                                  xout, gacc);
  finalize_ln<<<4096, 256, 0, stream>>>(xout, gacc, gamma, beta);
}